// Round 1
// baseline (249.118 us; speedup 1.0000x reference)
//
#include <hip/hip_runtime.h>
#include <stdint.h>

#define BATCH   262144
#define NROUTES 100000
#define NTIME   2016
#define DIM     256
#define KOUT    100
#define NTILES  7          // 112 padded output cols / 16

typedef __attribute__((ext_vector_type(2))) float f32x2;
typedef __attribute__((ext_vector_type(4))) float f32x4;

// ---- workspace layout ----
#define WS_WFRAG_BYTES ((size_t)(NTILES * 8 * 64 * 8))      // 28672 B fp8 w frags
#define WS_RA_OFF   (WS_WFRAG_BYTES)                        // f32 [NROUTES][8]
#define WS_TB_OFF   (WS_RA_OFF + (size_t)NROUTES * 32)      // f32 [NTIME][8]
#define WS_RT8_OFF  (WS_TB_OFF + (size_t)NTIME * 32)        // fp8 [NROUTES][256] permuted
#define WS_TT8_OFF  (WS_RT8_OFF + (size_t)NROUTES * 256)    // fp8 [NTIME][256] permuted
#define WS_NEED     (WS_TT8_OFF + (size_t)NTIME * 256)      // ~29.4 MB

// fused DPP lane-shift + add (pure VALU, no LDS)
template<int CTRL>
static __device__ __forceinline__ float dpp_add(float x) {
  int s = __builtin_amdgcn_update_dpp(0, __builtin_bit_cast(int, x), CTRL, 0xF, 0xF, true);
  return x + __builtin_bit_cast(float, s);
}
// full 64-lane sum -> lane 63
static __device__ __forceinline__ float wave_sum63(float x) {
  x = dpp_add<0x111>(x);  // row_shr:1
  x = dpp_add<0x112>(x);  // row_shr:2
  x = dpp_add<0x114>(x);  // row_shr:4
  x = dpp_add<0x118>(x);  // row_shr:8
  x = dpp_add<0x142>(x);  // row_bcast:15
  x = dpp_add<0x143>(x);  // row_bcast:31
  return x;
}
// 16-lane-group sum, broadcast to all 16 lanes
static __device__ __forceinline__ float sum16_all(float x) {
  x = dpp_add<0x0B1>(x);  // quad_perm [1,0,3,2]
  x = dpp_add<0x04E>(x);  // quad_perm [2,3,0,1]
  x = dpp_add<0x124>(x);  // row_ror:4
  x = dpp_add<0x128>(x);  // row_ror:8
  return x;
}
static __device__ __forceinline__ float sigm(float z) {
  return __builtin_amdgcn_rcpf(1.0f + __expf(-z));
}

// ---------------------------------------------------------------------------
// Prep: (1) w -> fp8 B-frag order (b<14), zero-padded cols 100..111
//       (2) TB + fp8 time table   (63 blocks, 32 rows)
//       (3) RA + fp8 route table  (3125 blocks, 32 rows)
// fp8 rows PERMUTED: logical k -> phys (ks>>1)*64 + quad*16 + (ks&1)*8 + j.
// We permute the LOAD side (lane l reads logical dword perm(l)) so the fp8
// store is a linear coalesced dword at byte 4*l.  Values scaled x8.
// ---------------------------------------------------------------------------
template<int DO8>
__global__ __launch_bounds__(256) void prep_kernel(
    const float* __restrict__ route_table,
    const float* __restrict__ time_table,
    const float* __restrict__ w,
    const float* __restrict__ mode_a,
    const float* __restrict__ mode_b,
    uint8_t* __restrict__ ws)
{
  const int b   = blockIdx.x;
  const int tid = threadIdx.x;

  if (b < 14) {                                   // ---- w fragments (fp8) ----
    const int u = b * 256 + tid;                  // [0, 3584)
    const int lane = u & 63;
    const int frag = u >> 6;                      // ks*7 + nt
    const int ks = frag / NTILES;
    const int nt = frag % NTILES;
    const int n  = nt * 16 + (lane & 15);
    const int k0 = ks * 32 + (lane >> 4) * 8;
    float v[8];
    #pragma unroll
    for (int j = 0; j < 8; ++j)
      v[j] = (n < KOUT) ? w[(size_t)(k0 + j) * KOUT + n] : 0.0f;
    uint32_t d0 = 0, d1 = 0;
    d0 = __builtin_amdgcn_cvt_pk_fp8_f32(v[0], v[1], d0, false);
    d0 = __builtin_amdgcn_cvt_pk_fp8_f32(v[2], v[3], d0, true);
    d1 = __builtin_amdgcn_cvt_pk_fp8_f32(v[4], v[5], d1, false);
    d1 = __builtin_amdgcn_cvt_pk_fp8_f32(v[6], v[7], d1, true);
    ((uint2*)ws)[u] = make_uint2(d0, d1);
    return;
  }

  const float* tab; const float* proj; float* outp; uint8_t* out8; int base;
  if (b < 14 + 63) {
    tab = time_table;  proj = mode_b; outp = (float*)(ws + WS_TB_OFF);
    out8 = ws + WS_TT8_OFF; base = (b - 14) * 32;
  } else {
    tab = route_table; proj = mode_a; outp = (float*)(ws + WS_RA_OFF);
    out8 = ws + WS_RT8_OFF; base = (b - 77) * 32;
  }

  const int wave = tid >> 6, lane = tid & 63;
  // inverse fragment permutation: lane l owns logical dword perm(l)
  const int perm = (2 * (lane >> 4) + ((lane >> 1) & 1)) * 8 +
                   ((lane >> 2) & 3) * 2 + (lane & 1);

  float A[4][5];                                  // proj rows 4*perm..4*perm+3
  #pragma unroll
  for (int j = 0; j < 4; ++j)
    #pragma unroll
    for (int i = 0; i < 5; ++i)
      A[j][i] = proj[(4 * perm + j) * 5 + i];

  const int row0 = base + wave * 8;               // 8 rows per wave
  float4 v[8];
  #pragma unroll
  for (int rr = 0; rr < 8; ++rr)
    v[rr] = *(const float4*)(tab + (size_t)(row0 + rr) * DIM + 4 * perm);

  #pragma unroll
  for (int rr = 0; rr < 8; ++rr) {
    const int row = row0 + rr;
    if (DO8) {                                    // fp8 emission, scaled x8
      uint32_t u = 0;
      u = __builtin_amdgcn_cvt_pk_fp8_f32(8.f * v[rr].x, 8.f * v[rr].y, u, false);
      u = __builtin_amdgcn_cvt_pk_fp8_f32(8.f * v[rr].z, 8.f * v[rr].w, u, true);
      *(uint32_t*)(out8 + (size_t)row * 256 + 4 * lane) = u;   // coalesced
    }
    float p[5];
    #pragma unroll
    for (int i = 0; i < 5; ++i) {
      float s = v[rr].x * A[0][i] + v[rr].y * A[1][i] + v[rr].z * A[2][i] + v[rr].w * A[3][i];
      p[i] = wave_sum63(s);
    }
    if (lane == 63) {
      float* o = outp + (size_t)row * 8;
      *(f32x4*)o = (f32x4){p[0], p[1], p[2], p[3]};
      o[4] = p[4];
    }
  }
}

// ---------------------------------------------------------------------------
// Main (fp8 path), PERSISTENT: exactly 768 blocks (3 blocks/CU at
// __launch_bounds__(256,3)) so there is NO partial second occupancy round.
// 3072 waves x {5 or 6} consecutive 16-sample tiles; 16384 = 1024*6 + 2048*5,
// the +1 tile strided wid%3==0 so per-block imbalance is <=1 tile.
// Same double-buffered gather pipeline as before; tile indices prefetched
// 1 tile ahead (rolling), all buffer indexing compile-time (no scratch).
// ---------------------------------------------------------------------------
__global__ __launch_bounds__(256, 3) void main_persistent(
    const int*   __restrict__ route_idx,
    const int*   __restrict__ time_idx,
    const float* __restrict__ mode_bias,
    const float* __restrict__ fc_w,
    const float* __restrict__ fc_b,
    const uint8_t* __restrict__ ws,
    float* __restrict__ out)
{
  __shared__ uint4 wlds[1792];                    // 28672 B fp8 w fragments
  const int tid  = threadIdx.x;
  const int wave = tid >> 6, lane = tid & 63;
  const int col  = lane & 15, quad = lane >> 4;

  const int wid = blockIdx.x * 4 + wave;          // 0..3071
  const int cnt = 5 + ((wid % 3) == 0 ? 1 : 0);   // tiles for this wave
  const int g0  = 5 * wid + (wid + 2) / 3;        // first tile index

  // ---- stage w fragments into LDS (coalesced, once per block) ----
  {
    const uint4* wsrc = (const uint4*)ws;
    #pragma unroll
    for (int j = 0; j < 7; ++j)
      wlds[j * 256 + tid] = wsrc[j * 256 + tid];
  }

  float fcw_l[NTILES];                            // fc_w with the 1/64 x-scale
  #pragma unroll
  for (int nt = 0; nt < NTILES; ++nt) {
    const int n = nt * 16 + col;
    fcw_l[nt] = (n < KOUT) ? fc_w[n] * 0.015625f : 0.0f;
  }
  const float fb = fc_b[0];

  // hoisted sigmoid-tail constants (loop-invariant across tiles)
  float bias_q[5], fcs_q[5];
  #pragma unroll
  for (int j = 0; j < 5; ++j) {
    bias_q[j] = mode_bias[5 * quad + j];
    fcs_q[j]  = fc_w[KOUT + 5 * quad + j];
  }
  const float bias20 = mode_bias[20 + quad];
  const float fcs20  = fc_w[KOUT + 20 + quad];
  const float bias24 = mode_bias[24];
  const float fcs24  = fc_w[KOUT + 24];

  uint4 rw0[4], tw0[4], rw1[4], tw1[4];           // ping-pong gather buffers

  auto issue = [&](uint4 (&rw)[4], uint4 (&tw)[4], int ri, int ti) {
    const uint8_t* rb = ws + WS_RT8_OFF + (size_t)ri * 256 + quad * 16;
    const uint8_t* tb = ws + WS_TT8_OFF + (size_t)ti * 256 + quad * 16;
    #pragma unroll
    for (int i = 0; i < 4; ++i) {
      rw[i] = *(const uint4*)(rb + i * 64);
      tw[i] = *(const uint4*)(tb + i * 64);
    }
  };

  const uint2* wl2 = (const uint2*)wlds;

  auto compute = [&](const uint4 (&rwb)[4], const uint4 (&twb)[4],
                     f32x4 raV, float raV4, f32x4 tbV, float tbV4, int T) {
    // ---- K-loop ----
    f32x4 acc[NTILES];
    #pragma unroll
    for (int nt = 0; nt < NTILES; ++nt) acc[nt] = (f32x4){0.f, 0.f, 0.f, 0.f};

    #pragma unroll
    for (int ks = 0; ks < 8; ++ks) {
      const int i = ks >> 1;
      const uint32_t ra = (ks & 1) ? rwb[i].z : rwb[i].x;
      const uint32_t rb = (ks & 1) ? rwb[i].w : rwb[i].y;
      const uint32_t ta = (ks & 1) ? twb[i].z : twb[i].x;
      const uint32_t tb = (ks & 1) ? twb[i].w : twb[i].y;
      f32x2 r01 = __builtin_amdgcn_cvt_pk_f32_fp8(ra, false);
      f32x2 r23 = __builtin_amdgcn_cvt_pk_f32_fp8(ra, true);
      f32x2 r45 = __builtin_amdgcn_cvt_pk_f32_fp8(rb, false);
      f32x2 r67 = __builtin_amdgcn_cvt_pk_f32_fp8(rb, true);
      f32x2 t01 = __builtin_amdgcn_cvt_pk_f32_fp8(ta, false);
      f32x2 t23 = __builtin_amdgcn_cvt_pk_f32_fp8(ta, true);
      f32x2 t45 = __builtin_amdgcn_cvt_pk_f32_fp8(tb, false);
      f32x2 t67 = __builtin_amdgcn_cvt_pk_f32_fp8(tb, true);
      f32x2 x01 = r01 * t01, x23 = r23 * t23, x45 = r45 * t45, x67 = r67 * t67;
      uint32_t p0 = 0, p1 = 0;
      p0 = __builtin_amdgcn_cvt_pk_fp8_f32(x01.x, x01.y, p0, false);
      p0 = __builtin_amdgcn_cvt_pk_fp8_f32(x23.x, x23.y, p0, true);
      p1 = __builtin_amdgcn_cvt_pk_fp8_f32(x45.x, x45.y, p1, false);
      p1 = __builtin_amdgcn_cvt_pk_fp8_f32(x67.x, x67.y, p1, true);
      const long a64 = __builtin_bit_cast(long, make_uint2(p0, p1));
      #pragma unroll
      for (int nt = 0; nt < NTILES; ++nt) {
        const long b64 = __builtin_bit_cast(long, wl2[(ks * NTILES + nt) * 64 + lane]);
        acc[nt] = __builtin_amdgcn_mfma_f32_16x16x32_fp8_fp8(a64, b64, acc[nt], 0, 0, 0);
      }
    }

    // ---- relu-dot with fc_w, reduced across the 16 col-lanes via DPP ----
    float s[4];
    #pragma unroll
    for (int reg = 0; reg < 4; ++reg) {
      float v = 0.f;
      #pragma unroll
      for (int nt = 0; nt < NTILES; ++nt)
        v += fmaxf(acc[nt][reg], 0.f) * fcw_l[nt];
      s[reg] = sum16_all(v);
    }

    // ---- sigmoid tail, distributed over the 4 quad-lanes of each sample ----
    const float rav[5] = {raV.x, raV.y, raV.z, raV.w, raV4};
    const float tbv[5] = {tbV.x, tbV.y, tbV.z, tbV.w, tbV4};
    const float rq = (quad & 2) ? ((quad & 1) ? rav[3] : rav[2])
                                : ((quad & 1) ? rav[1] : rav[0]);
    const float tq = (quad & 2) ? ((quad & 1) ? tbv[3] : tbv[2])
                                : ((quad & 1) ? tbv[1] : tbv[0]);
    float sig = 0.f;
    #pragma unroll
    for (int j = 0; j < 5; ++j)
      sig += sigm(rq * tbv[j] + bias_q[j]) * fcs_q[j];
    sig += sigm(rav[4] * tq + bias20) * fcs20;
    if (quad == 0)
      sig += sigm(rav[4] * tbv[4] + bias24) * fcs24;
    sig += __shfl_xor(sig, 16, 64);
    sig += __shfl_xor(sig, 32, 64);

    if (quad == (col >> 2)) {
      const float sa = (col & 1) ? s[1] : s[0];
      const float sb = (col & 1) ? s[3] : s[2];
      const float gcp = (col & 2) ? sb : sa;
      out[T * 16 + col] = fb + gcp + sig;
    }
  };

  // ---- software pipeline: ping-pong buffers, rolling 1-ahead idx prefetch ----
  int riA = route_idx[g0 * 16 + col];
  int tiA = time_idx[g0 * 16 + col];
  issue(rw0, tw0, riA, tiA);                      // tile g0 gathers in flight
  int riB = route_idx[(g0 + 1) * 16 + col];       // cnt >= 5, always valid
  int tiB = time_idx[(g0 + 1) * 16 + col];
  __syncthreads();                                // wlds ready

  int it = 0;
  while (true) {
    { // phase A: buffer 0, current idx (riA,tiA) = tile g0+it
      const float* rap = (const float*)(ws + WS_RA_OFF) + (size_t)riA * 8;
      const float* tbp = (const float*)(ws + WS_TB_OFF) + (size_t)tiA * 8;
      f32x4 raV = *(const f32x4*)rap; float raV4 = rap[4];
      f32x4 tbV = *(const f32x4*)tbp; float tbV4 = tbp[4];
      if (it + 1 < cnt) issue(rw1, tw1, riB, tiB);
      if (it + 2 < cnt) {
        riA = route_idx[(g0 + it + 2) * 16 + col];
        tiA = time_idx[(g0 + it + 2) * 16 + col];
      }
      compute(rw0, tw0, raV, raV4, tbV, tbV4, g0 + it);
    }
    ++it; if (it == cnt) break;
    { // phase B: buffer 1, current idx (riB,tiB) = tile g0+it
      const float* rap = (const float*)(ws + WS_RA_OFF) + (size_t)riB * 8;
      const float* tbp = (const float*)(ws + WS_TB_OFF) + (size_t)tiB * 8;
      f32x4 raV = *(const f32x4*)rap; float raV4 = rap[4];
      f32x4 tbV = *(const f32x4*)tbp; float tbV4 = tbp[4];
      if (it + 1 < cnt) issue(rw0, tw0, riA, tiA);
      if (it + 2 < cnt) {
        riB = route_idx[(g0 + it + 2) * 16 + col];
        tiB = time_idx[(g0 + it + 2) * 16 + col];
      }
      compute(rw1, tw1, raV, raV4, tbV, tbV4, g0 + it);
    }
    ++it; if (it == cnt) break;
  }
}

// ---------------------------------------------------------------------------
// Fallback (small ws): one tile per wave, gather f32 tables directly.
// ---------------------------------------------------------------------------
__global__ __launch_bounds__(256, 4) void main_fallback(
    const int*   __restrict__ route_idx,
    const int*   __restrict__ time_idx,
    const float* __restrict__ route_table,
    const float* __restrict__ time_table,
    const float* __restrict__ mode_bias,
    const float* __restrict__ fc_w,
    const float* __restrict__ fc_b,
    const uint8_t* __restrict__ ws,
    float* __restrict__ out)
{
  __shared__ uint4 wlds[1792];
  const int tid  = threadIdx.x;
  const int wave = tid >> 6, lane = tid & 63;
  const int col  = lane & 15, quad = lane >> 4;
  const int m0   = blockIdx.x * 64 + wave * 16;
  const size_t ri = (size_t)route_idx[m0 + col];
  const size_t ti = (size_t)time_idx[m0 + col];

  const float* rap = (const float*)(ws + WS_RA_OFF) + ri * 8;
  const float* tbp = (const float*)(ws + WS_TB_OFF) + ti * 8;
  f32x4 ra0 = *(const f32x4*)rap; float ra4 = rap[4];
  f32x4 tb0 = *(const f32x4*)tbp; float tb4 = tbp[4];

  {
    const uint4* wsrc = (const uint4*)ws;
    #pragma unroll
    for (int j = 0; j < 7; ++j)
      wlds[j * 256 + tid] = wsrc[j * 256 + tid];
  }
  __syncthreads();

  float fcw_l[NTILES];
  #pragma unroll
  for (int nt = 0; nt < NTILES; ++nt) {
    const int n = nt * 16 + col;
    fcw_l[nt] = (n < KOUT) ? fc_w[n] * 0.015625f : 0.0f;
  }

  f32x4 acc[NTILES];
  #pragma unroll
  for (int nt = 0; nt < NTILES; ++nt) acc[nt] = (f32x4){0.f, 0.f, 0.f, 0.f};
  const uint2* wl2 = (const uint2*)wlds;

  #pragma unroll
  for (int ks = 0; ks < 8; ++ks) {
    const float4* rp = (const float4*)(route_table + ri * DIM + ks * 32 + quad * 8);
    const float4* tp = (const float4*)(time_table  + ti * DIM + ks * 32 + quad * 8);
    float4 r0 = rp[0], r1 = rp[1], t0 = tp[0], t1 = tp[1];
    uint32_t p0 = 0, p1 = 0;
    p0 = __builtin_amdgcn_cvt_pk_fp8_f32(64.f * r0.x * t0.x, 64.f * r0.y * t0.y, p0, false);
    p0 = __builtin_amdgcn_cvt_pk_fp8_f32(64.f * r0.z * t0.z, 64.f * r0.w * t0.w, p0, true);
    p1 = __builtin_amdgcn_cvt_pk_fp8_f32(64.f * r1.x * t1.x, 64.f * r1.y * t1.y, p1, false);
    p1 = __builtin_amdgcn_cvt_pk_fp8_f32(64.f * r1.z * t1.z, 64.f * r1.w * t1.w, p1, true);
    const long a64 = __builtin_bit_cast(long, make_uint2(p0, p1));
    #pragma unroll
    for (int nt = 0; nt < NTILES; ++nt) {
      const long b64 = __builtin_bit_cast(long, wl2[(ks * NTILES + nt) * 64 + lane]);
      acc[nt] = __builtin_amdgcn_mfma_f32_16x16x32_fp8_fp8(a64, b64, acc[nt], 0, 0, 0);
    }
  }

  float s[4];
  #pragma unroll
  for (int reg = 0; reg < 4; ++reg) {
    float v = 0.f;
    #pragma unroll
    for (int nt = 0; nt < NTILES; ++nt)
      v += fmaxf(acc[nt][reg], 0.f) * fcw_l[nt];
    s[reg] = sum16_all(v);
  }

  const float rav[5] = {ra0.x, ra0.y, ra0.z, ra0.w, ra4};
  const float tbv[5] = {tb0.x, tb0.y, tb0.z, tb0.w, tb4};
  const float rq = (quad & 2) ? ((quad & 1) ? rav[3] : rav[2])
                              : ((quad & 1) ? rav[1] : rav[0]);
  const float tq = (quad & 2) ? ((quad & 1) ? tbv[3] : tbv[2])
                              : ((quad & 1) ? tbv[1] : tbv[0]);
  float sig = 0.f;
  #pragma unroll
  for (int j = 0; j < 5; ++j)
    sig += sigm(rq * tbv[j] + mode_bias[5 * quad + j]) * fc_w[KOUT + 5 * quad + j];
  sig += sigm(rav[4] * tq + mode_bias[20 + quad]) * fc_w[KOUT + 20 + quad];
  if (quad == 0)
    sig += sigm(rav[4] * tbv[4] + mode_bias[24]) * fc_w[KOUT + 24];
  sig += __shfl_xor(sig, 16, 64);
  sig += __shfl_xor(sig, 32, 64);

  if (quad == (col >> 2)) {
    const float sa = (col & 1) ? s[1] : s[0];
    const float sb = (col & 1) ? s[3] : s[2];
    const float gcp = (col & 2) ? sb : sa;
    out[m0 + col] = fc_b[0] + gcp + sig;
  }
}

// ---------------------------------------------------------------------------
extern "C" void kernel_launch(void* const* d_in, const int* in_sizes, int n_in,
                              void* d_out, int out_size, void* d_ws, size_t ws_size,
                              hipStream_t stream)
{
  const int*   route_idx   = (const int*)d_in[0];
  const int*   time_idx    = (const int*)d_in[1];
  const float* route_table = (const float*)d_in[2];
  const float* time_table  = (const float*)d_in[3];
  const float* w           = (const float*)d_in[4];
  const float* mode_a      = (const float*)d_in[5];
  const float* mode_b      = (const float*)d_in[6];
  const float* mode_bias   = (const float*)d_in[7];
  const float* fc_w        = (const float*)d_in[8];
  const float* fc_b        = (const float*)d_in[9];
  uint8_t* ws  = (uint8_t*)d_ws;
  float*   out = (float*)d_out;

  const int big = (ws_size >= WS_NEED) ? 1 : 0;   // constant across calls

  // 14 (w frags) + 63 (time, 32 rows/blk) + 3125 (route, 32 rows/blk)
  if (big) {
    prep_kernel<1><<<3202, 256, 0, stream>>>(route_table, time_table, w,
                                             mode_a, mode_b, ws);
    // 768 blocks = 3 blocks/CU x 256 CUs: single occupancy round, no tail
    main_persistent<<<768, 256, 0, stream>>>(route_idx, time_idx,
                                             mode_bias, fc_w, fc_b, ws, out);
  } else {
    prep_kernel<0><<<3202, 256, 0, stream>>>(route_table, time_table, w,
                                             mode_a, mode_b, ws);
    main_fallback<<<BATCH / 64, 256, 0, stream>>>(route_idx, time_idx,
                                                  route_table, time_table,
                                                  mode_bias, fc_w, fc_b, ws, out);
  }
}

// Round 2
// 199.497 us; speedup vs baseline: 1.2487x; 1.2487x over previous
//
#include <hip/hip_runtime.h>
#include <stdint.h>

#define BATCH   262144
#define NROUTES 100000
#define NTIME   2016
#define DIM     256
#define KOUT    100
#define NTILES  7          // 112 padded output cols / 16

typedef __attribute__((ext_vector_type(2))) float f32x2;
typedef __attribute__((ext_vector_type(4))) float f32x4;

// ---- workspace layout ----
#define WS_WFRAG_BYTES ((size_t)(NTILES * 8 * 64 * 8))      // 28672 B fp8 w frags
#define WS_RA_OFF   (WS_WFRAG_BYTES)                        // f32 [NROUTES][8]
#define WS_TB_OFF   (WS_RA_OFF + (size_t)NROUTES * 32)      // f32 [NTIME][8]
#define WS_RT8_OFF  (WS_TB_OFF + (size_t)NTIME * 32)        // fp8 [NROUTES][256] permuted
#define WS_TT8_OFF  (WS_RT8_OFF + (size_t)NROUTES * 256)    // fp8 [NTIME][256] permuted
#define WS_NEED     (WS_TT8_OFF + (size_t)NTIME * 256)      // ~29.4 MB

// fused DPP lane-shift + add (pure VALU, no LDS)
template<int CTRL>
static __device__ __forceinline__ float dpp_add(float x) {
  int s = __builtin_amdgcn_update_dpp(0, __builtin_bit_cast(int, x), CTRL, 0xF, 0xF, true);
  return x + __builtin_bit_cast(float, s);
}
// full 64-lane sum -> lane 63
static __device__ __forceinline__ float wave_sum63(float x) {
  x = dpp_add<0x111>(x);  // row_shr:1
  x = dpp_add<0x112>(x);  // row_shr:2
  x = dpp_add<0x114>(x);  // row_shr:4
  x = dpp_add<0x118>(x);  // row_shr:8
  x = dpp_add<0x142>(x);  // row_bcast:15
  x = dpp_add<0x143>(x);  // row_bcast:31
  return x;
}
// 16-lane-group sum, broadcast to all 16 lanes
static __device__ __forceinline__ float sum16_all(float x) {
  x = dpp_add<0x0B1>(x);  // quad_perm [1,0,3,2]
  x = dpp_add<0x04E>(x);  // quad_perm [2,3,0,1]
  x = dpp_add<0x124>(x);  // row_ror:4
  x = dpp_add<0x128>(x);  // row_ror:8
  return x;
}
static __device__ __forceinline__ float sigm(float z) {
  return __builtin_amdgcn_rcpf(1.0f + __expf(-z));
}

// ---------------------------------------------------------------------------
// Prep: (1) w -> fp8 B-frag order (b<14), zero-padded cols 100..111
//       (2) TB + fp8 time table   (63 blocks, 32 rows)
//       (3) RA + fp8 route table  (3125 blocks, 32 rows)
// fp8 rows PERMUTED: logical k -> phys (ks>>1)*64 + quad*16 + (ks&1)*8 + j.
// We permute the LOAD side (lane l reads logical dword perm(l)) so the fp8
// store is a linear coalesced dword at byte 4*l.  Values scaled x8.
// ---------------------------------------------------------------------------
template<int DO8>
__global__ __launch_bounds__(256) void prep_kernel(
    const float* __restrict__ route_table,
    const float* __restrict__ time_table,
    const float* __restrict__ w,
    const float* __restrict__ mode_a,
    const float* __restrict__ mode_b,
    uint8_t* __restrict__ ws)
{
  const int b   = blockIdx.x;
  const int tid = threadIdx.x;

  if (b < 14) {                                   // ---- w fragments (fp8) ----
    const int u = b * 256 + tid;                  // [0, 3584)
    const int lane = u & 63;
    const int frag = u >> 6;                      // ks*7 + nt
    const int ks = frag / NTILES;
    const int nt = frag % NTILES;
    const int n  = nt * 16 + (lane & 15);
    const int k0 = ks * 32 + (lane >> 4) * 8;
    float v[8];
    #pragma unroll
    for (int j = 0; j < 8; ++j)
      v[j] = (n < KOUT) ? w[(size_t)(k0 + j) * KOUT + n] : 0.0f;
    uint32_t d0 = 0, d1 = 0;
    d0 = __builtin_amdgcn_cvt_pk_fp8_f32(v[0], v[1], d0, false);
    d0 = __builtin_amdgcn_cvt_pk_fp8_f32(v[2], v[3], d0, true);
    d1 = __builtin_amdgcn_cvt_pk_fp8_f32(v[4], v[5], d1, false);
    d1 = __builtin_amdgcn_cvt_pk_fp8_f32(v[6], v[7], d1, true);
    ((uint2*)ws)[u] = make_uint2(d0, d1);
    return;
  }

  const float* tab; const float* proj; float* outp; uint8_t* out8; int base;
  if (b < 14 + 63) {
    tab = time_table;  proj = mode_b; outp = (float*)(ws + WS_TB_OFF);
    out8 = ws + WS_TT8_OFF; base = (b - 14) * 32;
  } else {
    tab = route_table; proj = mode_a; outp = (float*)(ws + WS_RA_OFF);
    out8 = ws + WS_RT8_OFF; base = (b - 77) * 32;
  }

  const int wave = tid >> 6, lane = tid & 63;
  // inverse fragment permutation: lane l owns logical dword perm(l)
  const int perm = (2 * (lane >> 4) + ((lane >> 1) & 1)) * 8 +
                   ((lane >> 2) & 3) * 2 + (lane & 1);

  float A[4][5];                                  // proj rows 4*perm..4*perm+3
  #pragma unroll
  for (int j = 0; j < 4; ++j)
    #pragma unroll
    for (int i = 0; i < 5; ++i)
      A[j][i] = proj[(4 * perm + j) * 5 + i];

  const int row0 = base + wave * 8;               // 8 rows per wave
  float4 v[8];
  #pragma unroll
  for (int rr = 0; rr < 8; ++rr)
    v[rr] = *(const float4*)(tab + (size_t)(row0 + rr) * DIM + 4 * perm);

  #pragma unroll
  for (int rr = 0; rr < 8; ++rr) {
    const int row = row0 + rr;
    if (DO8) {                                    // fp8 emission, scaled x8
      uint32_t u = 0;
      u = __builtin_amdgcn_cvt_pk_fp8_f32(8.f * v[rr].x, 8.f * v[rr].y, u, false);
      u = __builtin_amdgcn_cvt_pk_fp8_f32(8.f * v[rr].z, 8.f * v[rr].w, u, true);
      *(uint32_t*)(out8 + (size_t)row * 256 + 4 * lane) = u;   // coalesced
    }
    float p[5];
    #pragma unroll
    for (int i = 0; i < 5; ++i) {
      float s = v[rr].x * A[0][i] + v[rr].y * A[1][i] + v[rr].z * A[2][i] + v[rr].w * A[3][i];
      p[i] = wave_sum63(s);
    }
    if (lane == 63) {
      float* o = outp + (size_t)row * 8;
      *(f32x4*)o = (f32x4){p[0], p[1], p[2], p[3]};
      o[4] = p[4];
    }
  }
}

// ---------------------------------------------------------------------------
// Main (fp8 path): each wave owns 4 consecutive 16-sample tiles, software-
// pipelined, FULLY UNROLLED (compile-time buffer indices keep both ping-pong
// buffers register-resident — a runtime-bounded loop loses the pipeline;
// measured: VGPR dropped to 84 and gathers serialized, +50% regression).
// __launch_bounds__(256,4): VGPR capped at 128 so 4 blocks/CU are resident;
// grid 1024 = 4 x 256 CUs -> exactly one occupancy round, zero tail.
// ---------------------------------------------------------------------------
__global__ __launch_bounds__(256, 4) void main_pipelined(
    const int*   __restrict__ route_idx,
    const int*   __restrict__ time_idx,
    const float* __restrict__ mode_bias,
    const float* __restrict__ fc_w,
    const float* __restrict__ fc_b,
    const uint8_t* __restrict__ ws,
    float* __restrict__ out)
{
  __shared__ uint4 wlds[1792];                    // 28672 B fp8 w fragments
  const int tid  = threadIdx.x;
  const int wave = tid >> 6, lane = tid & 63;
  const int col  = lane & 15, quad = lane >> 4;
  const int base = (blockIdx.x * 4 + wave) * 64;  // 4 tiles x 16 samples

  // ---- all tile indices up front (no mid-pipeline idx chains) ----
  int ri[4], ti[4];
  #pragma unroll
  for (int t = 0; t < 4; ++t) {
    ri[t] = route_idx[base + t * 16 + col];
    ti[t] = time_idx[base + t * 16 + col];
  }

  // ---- stage w fragments into LDS (coalesced, once per block) ----
  {
    const uint4* wsrc = (const uint4*)ws;
    #pragma unroll
    for (int j = 0; j < 7; ++j)
      wlds[j * 256 + tid] = wsrc[j * 256 + tid];
  }

  float fcw_l[NTILES];                            // fc_w with the 1/64 x-scale
  #pragma unroll
  for (int nt = 0; nt < NTILES; ++nt) {
    const int n = nt * 16 + col;
    fcw_l[nt] = (n < KOUT) ? fc_w[n] * 0.015625f : 0.0f;
  }
  const float fb = fc_b[0];

  uint4 rw[2][4], tw[2][4];                       // double-buffered gathers
  auto issue = [&](int buf, int t) {
    const uint8_t* rb = ws + WS_RT8_OFF + (size_t)ri[t] * 256 + quad * 16;
    const uint8_t* tb = ws + WS_TT8_OFF + (size_t)ti[t] * 256 + quad * 16;
    #pragma unroll
    for (int i = 0; i < 4; ++i) {
      rw[buf][i] = *(const uint4*)(rb + i * 64);
      tw[buf][i] = *(const uint4*)(tb + i * 64);
    }
  };

  issue(0, 0);                                    // tile0 gathers in flight
  __syncthreads();                                // wlds ready

  const uint2* wl2 = (const uint2*)wlds;

  #pragma unroll
  for (int it = 0; it < 4; ++it) {
    const int cb = it & 1, nb = cb ^ 1;

    // RA/TB for CURRENT tile first (oldest), then next tile's gathers —
    // epilogue's RA/TB wait leaves the next gathers in flight.
    const float* rap = (const float*)(ws + WS_RA_OFF) + (size_t)ri[it] * 8;
    const float* tbp = (const float*)(ws + WS_TB_OFF) + (size_t)ti[it] * 8;
    f32x4 ra0 = *(const f32x4*)rap; float ra4 = rap[4];
    f32x4 tb0 = *(const f32x4*)tbp; float tb4 = tbp[4];
    if (it < 3) issue(nb, it + 1);

    // ---- K-loop on buffer cb ----
    f32x4 acc[NTILES];
    #pragma unroll
    for (int nt = 0; nt < NTILES; ++nt) acc[nt] = (f32x4){0.f, 0.f, 0.f, 0.f};

    #pragma unroll
    for (int ks = 0; ks < 8; ++ks) {
      const int i = ks >> 1;
      const uint32_t ra = (ks & 1) ? rw[cb][i].z : rw[cb][i].x;
      const uint32_t rb = (ks & 1) ? rw[cb][i].w : rw[cb][i].y;
      const uint32_t ta = (ks & 1) ? tw[cb][i].z : tw[cb][i].x;
      const uint32_t tb = (ks & 1) ? tw[cb][i].w : tw[cb][i].y;
      f32x2 r01 = __builtin_amdgcn_cvt_pk_f32_fp8(ra, false);
      f32x2 r23 = __builtin_amdgcn_cvt_pk_f32_fp8(ra, true);
      f32x2 r45 = __builtin_amdgcn_cvt_pk_f32_fp8(rb, false);
      f32x2 r67 = __builtin_amdgcn_cvt_pk_f32_fp8(rb, true);
      f32x2 t01 = __builtin_amdgcn_cvt_pk_f32_fp8(ta, false);
      f32x2 t23 = __builtin_amdgcn_cvt_pk_f32_fp8(ta, true);
      f32x2 t45 = __builtin_amdgcn_cvt_pk_f32_fp8(tb, false);
      f32x2 t67 = __builtin_amdgcn_cvt_pk_f32_fp8(tb, true);
      f32x2 x01 = r01 * t01, x23 = r23 * t23, x45 = r45 * t45, x67 = r67 * t67;
      uint32_t p0 = 0, p1 = 0;
      p0 = __builtin_amdgcn_cvt_pk_fp8_f32(x01.x, x01.y, p0, false);
      p0 = __builtin_amdgcn_cvt_pk_fp8_f32(x23.x, x23.y, p0, true);
      p1 = __builtin_amdgcn_cvt_pk_fp8_f32(x45.x, x45.y, p1, false);
      p1 = __builtin_amdgcn_cvt_pk_fp8_f32(x67.x, x67.y, p1, true);
      const long a64 = __builtin_bit_cast(long, make_uint2(p0, p1));
      #pragma unroll
      for (int nt = 0; nt < NTILES; ++nt) {
        const long b64 = __builtin_bit_cast(long, wl2[(ks * NTILES + nt) * 64 + lane]);
        acc[nt] = __builtin_amdgcn_mfma_f32_16x16x32_fp8_fp8(a64, b64, acc[nt], 0, 0, 0);
      }
    }

    // ---- relu-dot with fc_w, reduced across the 16 col-lanes via DPP ----
    float s[4];
    #pragma unroll
    for (int reg = 0; reg < 4; ++reg) {
      float v = 0.f;
      #pragma unroll
      for (int nt = 0; nt < NTILES; ++nt)
        v += fmaxf(acc[nt][reg], 0.f) * fcw_l[nt];
      s[reg] = sum16_all(v);
    }

    // ---- sigmoid tail, distributed over the 4 quad-lanes of each sample ----
    const float rav[5] = {ra0.x, ra0.y, ra0.z, ra0.w, ra4};
    const float tbv[5] = {tb0.x, tb0.y, tb0.z, tb0.w, tb4};
    const float rq = (quad & 2) ? ((quad & 1) ? rav[3] : rav[2])
                                : ((quad & 1) ? rav[1] : rav[0]);
    const float tq = (quad & 2) ? ((quad & 1) ? tbv[3] : tbv[2])
                                : ((quad & 1) ? tbv[1] : tbv[0]);
    float sig = 0.f;
    #pragma unroll
    for (int j = 0; j < 5; ++j)
      sig += sigm(rq * tbv[j] + mode_bias[5 * quad + j]) * fc_w[KOUT + 5 * quad + j];
    sig += sigm(rav[4] * tq + mode_bias[20 + quad]) * fc_w[KOUT + 20 + quad];
    if (quad == 0)
      sig += sigm(rav[4] * tbv[4] + mode_bias[24]) * fc_w[KOUT + 24];
    sig += __shfl_xor(sig, 16, 64);
    sig += __shfl_xor(sig, 32, 64);

    if (quad == (col >> 2)) {
      const float sa = (col & 1) ? s[1] : s[0];
      const float sb = (col & 1) ? s[3] : s[2];
      const float gcp = (col & 2) ? sb : sa;
      out[base + it * 16 + col] = fb + gcp + sig;
    }
  }
}

// ---------------------------------------------------------------------------
// Fallback (small ws): one tile per wave, gather f32 tables directly.
// ---------------------------------------------------------------------------
__global__ __launch_bounds__(256, 4) void main_fallback(
    const int*   __restrict__ route_idx,
    const int*   __restrict__ time_idx,
    const float* __restrict__ route_table,
    const float* __restrict__ time_table,
    const float* __restrict__ mode_bias,
    const float* __restrict__ fc_w,
    const float* __restrict__ fc_b,
    const uint8_t* __restrict__ ws,
    float* __restrict__ out)
{
  __shared__ uint4 wlds[1792];
  const int tid  = threadIdx.x;
  const int wave = tid >> 6, lane = tid & 63;
  const int col  = lane & 15, quad = lane >> 4;
  const int m0   = blockIdx.x * 64 + wave * 16;
  const size_t ri = (size_t)route_idx[m0 + col];
  const size_t ti = (size_t)time_idx[m0 + col];

  const float* rap = (const float*)(ws + WS_RA_OFF) + ri * 8;
  const float* tbp = (const float*)(ws + WS_TB_OFF) + ti * 8;
  f32x4 ra0 = *(const f32x4*)rap; float ra4 = rap[4];
  f32x4 tb0 = *(const f32x4*)tbp; float tb4 = tbp[4];

  {
    const uint4* wsrc = (const uint4*)ws;
    #pragma unroll
    for (int j = 0; j < 7; ++j)
      wlds[j * 256 + tid] = wsrc[j * 256 + tid];
  }
  __syncthreads();

  float fcw_l[NTILES];
  #pragma unroll
  for (int nt = 0; nt < NTILES; ++nt) {
    const int n = nt * 16 + col;
    fcw_l[nt] = (n < KOUT) ? fc_w[n] * 0.015625f : 0.0f;
  }

  f32x4 acc[NTILES];
  #pragma unroll
  for (int nt = 0; nt < NTILES; ++nt) acc[nt] = (f32x4){0.f, 0.f, 0.f, 0.f};
  const uint2* wl2 = (const uint2*)wlds;

  #pragma unroll
  for (int ks = 0; ks < 8; ++ks) {
    const float4* rp = (const float4*)(route_table + ri * DIM + ks * 32 + quad * 8);
    const float4* tp = (const float4*)(time_table  + ti * DIM + ks * 32 + quad * 8);
    float4 r0 = rp[0], r1 = rp[1], t0 = tp[0], t1 = tp[1];
    uint32_t p0 = 0, p1 = 0;
    p0 = __builtin_amdgcn_cvt_pk_fp8_f32(64.f * r0.x * t0.x, 64.f * r0.y * t0.y, p0, false);
    p0 = __builtin_amdgcn_cvt_pk_fp8_f32(64.f * r0.z * t0.z, 64.f * r0.w * t0.w, p0, true);
    p1 = __builtin_amdgcn_cvt_pk_fp8_f32(64.f * r1.x * t1.x, 64.f * r1.y * t1.y, p1, false);
    p1 = __builtin_amdgcn_cvt_pk_fp8_f32(64.f * r1.z * t1.z, 64.f * r1.w * t1.w, p1, true);
    const long a64 = __builtin_bit_cast(long, make_uint2(p0, p1));
    #pragma unroll
    for (int nt = 0; nt < NTILES; ++nt) {
      const long b64 = __builtin_bit_cast(long, wl2[(ks * NTILES + nt) * 64 + lane]);
      acc[nt] = __builtin_amdgcn_mfma_f32_16x16x32_fp8_fp8(a64, b64, acc[nt], 0, 0, 0);
    }
  }

  float s[4];
  #pragma unroll
  for (int reg = 0; reg < 4; ++reg) {
    float v = 0.f;
    #pragma unroll
    for (int nt = 0; nt < NTILES; ++nt)
      v += fmaxf(acc[nt][reg], 0.f) * fcw_l[nt];
    s[reg] = sum16_all(v);
  }

  const float rav[5] = {ra0.x, ra0.y, ra0.z, ra0.w, ra4};
  const float tbv[5] = {tb0.x, tb0.y, tb0.z, tb0.w, tb4};
  const float rq = (quad & 2) ? ((quad & 1) ? rav[3] : rav[2])
                              : ((quad & 1) ? rav[1] : rav[0]);
  const float tq = (quad & 2) ? ((quad & 1) ? tbv[3] : tbv[2])
                              : ((quad & 1) ? tbv[1] : tbv[0]);
  float sig = 0.f;
  #pragma unroll
  for (int j = 0; j < 5; ++j)
    sig += sigm(rq * tbv[j] + mode_bias[5 * quad + j]) * fc_w[KOUT + 5 * quad + j];
  sig += sigm(rav[4] * tq + mode_bias[20 + quad]) * fc_w[KOUT + 20 + quad];
  if (quad == 0)
    sig += sigm(rav[4] * tbv[4] + mode_bias[24]) * fc_w[KOUT + 24];
  sig += __shfl_xor(sig, 16, 64);
  sig += __shfl_xor(sig, 32, 64);

  if (quad == (col >> 2)) {
    const float sa = (col & 1) ? s[1] : s[0];
    const float sb = (col & 1) ? s[3] : s[2];
    const float gcp = (col & 2) ? sb : sa;
    out[m0 + col] = fc_b[0] + gcp + sig;
  }
}

// ---------------------------------------------------------------------------
extern "C" void kernel_launch(void* const* d_in, const int* in_sizes, int n_in,
                              void* d_out, int out_size, void* d_ws, size_t ws_size,
                              hipStream_t stream)
{
  const int*   route_idx   = (const int*)d_in[0];
  const int*   time_idx    = (const int*)d_in[1];
  const float* route_table = (const float*)d_in[2];
  const float* time_table  = (const float*)d_in[3];
  const float* w           = (const float*)d_in[4];
  const float* mode_a      = (const float*)d_in[5];
  const float* mode_b      = (const float*)d_in[6];
  const float* mode_bias   = (const float*)d_in[7];
  const float* fc_w        = (const float*)d_in[8];
  const float* fc_b        = (const float*)d_in[9];
  uint8_t* ws  = (uint8_t*)d_ws;
  float*   out = (float*)d_out;

  const int big = (ws_size >= WS_NEED) ? 1 : 0;   // constant across calls

  // 14 (w frags) + 63 (time, 32 rows/blk) + 3125 (route, 32 rows/blk)
  if (big) {
    prep_kernel<1><<<3202, 256, 0, stream>>>(route_table, time_table, w,
                                             mode_a, mode_b, ws);
    // 1024 blocks = 4 blocks/CU x 256 CUs at (256,4): single round, no tail
    main_pipelined<<<BATCH / 256, 256, 0, stream>>>(route_idx, time_idx,
                                                    mode_bias, fc_w, fc_b, ws, out);
  } else {
    prep_kernel<0><<<3202, 256, 0, stream>>>(route_table, time_table, w,
                                             mode_a, mode_b, ws);
    main_fallback<<<BATCH / 64, 256, 0, stream>>>(route_idx, time_idx,
                                                  route_table, time_table,
                                                  mode_bias, fc_w, fc_b, ws, out);
  }
}